// Round 2
// baseline (3447.144 us; speedup 1.0000x reference)
//
#include <hip/hip_runtime.h>
#include <math.h>

// Problem constants: B=4, T=8, C=d=256, H=W=48, L=2, nh=8, dk=32
#define SEQ   9216          // B*H*W
#define TOK   73728         // SEQ*T
#define SBUF  18874368      // TOK*256 floats, one full activation buffer

// ---------------------------------------------------------------------------
// Positional-encoding table: pe[t*256 + c]
__global__ void pe_fill(float* __restrict__ pe) {
    int idx = blockIdx.x * 256 + threadIdx.x;   // 0..2047
    int t = idx >> 8, c = idx & 255;
    int i2 = c & ~1;                            // 2i (pairs share the freq)
    float div = __expf((float)i2 * (-logf(10000.f) / 256.f));
    float ang = (float)t * div;
    pe[idx] = (c & 1) ? cosf(ang) : sinf(ang);
}

// ---------------------------------------------------------------------------
// x (B,T,C,H,W) -> h (n, t, c) with h += pe[t,c].  LDS-tiled (c,w).
__global__ __launch_bounds__(256) void transpose_in(const float* __restrict__ x,
                                                    const float* __restrict__ pe,
                                                    float* __restrict__ h) {
    // grid.x = b*t*y (1536), grid.y = c-tile (8), grid.z = w-tile (2)
    int bty = blockIdx.x;
    int y = bty % 48; int bt = bty / 48; int t = bt & 7; int b = bt >> 3;
    int c0 = blockIdx.y * 32, w0 = blockIdx.z * 32;
    __shared__ float tile[32][33];              // [c_local][w_local]
    int tid = threadIdx.x;
    const float* xp = x + ((size_t)(b * 8 + t) * 256) * 2304 + (size_t)y * 48;
    int wl = tid & 31, cl8 = tid >> 5;
#pragma unroll
    for (int it = 0; it < 4; ++it) {
        int c = c0 + it * 8 + cl8;
        int w = w0 + wl;
        if (w < 48) tile[it * 8 + cl8][wl] = xp[(size_t)c * 2304 + w] + pe[t * 256 + c];
    }
    __syncthreads();
    int cl = tid & 31, wl8 = tid >> 5;
#pragma unroll
    for (int it = 0; it < 4; ++it) {
        int w = w0 + it * 8 + wl8;
        int c = c0 + cl;
        if (w < 48) {
            size_t n = (size_t)(b * 48 + y) * 48 + w;
            h[(n * 8 + t) * 256 + c] = tile[cl][it * 8 + wl8];
        }
    }
}

// ---------------------------------------------------------------------------
// out (B,C,H,W) = h[n, T-1, c].  LDS-tiled.
__global__ __launch_bounds__(256) void transpose_out(const float* __restrict__ h,
                                                     float* __restrict__ out) {
    int by = blockIdx.x; int y = by % 48, b = by / 48;
    int c0 = blockIdx.y * 32, w0 = blockIdx.z * 32;
    __shared__ float tile[32][33];              // [w_local][c_local]
    int tid = threadIdx.x;
    int cl = tid & 31, wl8 = tid >> 5;
#pragma unroll
    for (int it = 0; it < 4; ++it) {
        int w = w0 + it * 8 + wl8;
        if (w < 48) {
            size_t n = (size_t)(b * 48 + y) * 48 + w;
            tile[it * 8 + wl8][cl] = h[n * 2048 + 1792 + c0 + cl];
        }
    }
    __syncthreads();
    int wl = tid & 31, cl8 = tid >> 5;
#pragma unroll
    for (int it = 0; it < 4; ++it) {
        int c = c0 + it * 8 + cl8;
        int w = w0 + wl;
        if (w < 48)
            out[((size_t)(b * 256 + c) * 48 + y) * 48 + w] = tile[wl][it * 8 + cl8];
    }
}

// ---------------------------------------------------------------------------
// C[M,N] = A[M,K] @ W[N,K]^T + bias, optional exact-erf GELU.
// 128x128 block tile, 256 threads, 8x8 microtile split 4+4 so LDS fragment
// reads are float4 with <=2-way bank aliasing (free per m136).
template <int ACT>
__global__ __launch_bounds__(256) void gemm_kernel(const float* __restrict__ A,
                                                   const float* __restrict__ W,
                                                   const float* __restrict__ bias,
                                                   float* __restrict__ C,
                                                   int M, int N, int K) {
    __shared__ float As[16][132];   // [k_local][row], padded
    __shared__ float Bs[16][132];   // [k_local][col]
    int tid = threadIdx.x;
    int m0 = blockIdx.y * 128, n0 = blockIdx.x * 128;
    int i = tid & 15, j = tid >> 4;
    float acc[8][8] = {};
    const float* Ab = A + (size_t)m0 * K;
    const float* Wb = W + (size_t)n0 * K;
    for (int k0 = 0; k0 < K; k0 += 16) {
#pragma unroll
        for (int half = 0; half < 2; ++half) {
            int idx = tid + half * 256;
            int r = idx >> 2, cq = idx & 3;
            float4 av = *(const float4*)&Ab[(size_t)r * K + k0 + cq * 4];
            float4 bv = *(const float4*)&Wb[(size_t)r * K + k0 + cq * 4];
            As[cq * 4 + 0][r] = av.x; As[cq * 4 + 1][r] = av.y;
            As[cq * 4 + 2][r] = av.z; As[cq * 4 + 3][r] = av.w;
            Bs[cq * 4 + 0][r] = bv.x; Bs[cq * 4 + 1][r] = bv.y;
            Bs[cq * 4 + 2][r] = bv.z; Bs[cq * 4 + 3][r] = bv.w;
        }
        __syncthreads();
#pragma unroll
        for (int kk = 0; kk < 16; ++kk) {
            float4 a0 = *(const float4*)&As[kk][i * 4];
            float4 a1 = *(const float4*)&As[kk][i * 4 + 64];
            float4 b0 = *(const float4*)&Bs[kk][j * 4];
            float4 b1 = *(const float4*)&Bs[kk][j * 4 + 64];
            float ar[8] = {a0.x, a0.y, a0.z, a0.w, a1.x, a1.y, a1.z, a1.w};
            float br[8] = {b0.x, b0.y, b0.z, b0.w, b1.x, b1.y, b1.z, b1.w};
#pragma unroll
            for (int r = 0; r < 8; ++r)
#pragma unroll
                for (int c = 0; c < 8; ++c) acc[r][c] += ar[r] * br[c];
        }
        __syncthreads();
    }
#pragma unroll
    for (int r = 0; r < 8; ++r) {
        int row = m0 + i * 4 + (r & 3) + ((r >> 2) << 6);
#pragma unroll
        for (int ch = 0; ch < 2; ++ch) {
            int col = n0 + j * 4 + (ch << 6);
            float4 v;
            float* vp = &v.x;
#pragma unroll
            for (int e = 0; e < 4; ++e) {
                float val = acc[r][ch * 4 + e] + bias[col + e];
                if (ACT) val = 0.5f * val * (1.0f + erff(val * 0.70710678118654752f));
                vp[e] = val;
            }
            *(float4*)&C[(size_t)row * N + col] = v;
        }
    }
}

// ---------------------------------------------------------------------------
// Causal MHSA: one block per sequence; 4 waves x 2 heads each.
// lane = t*8+s computes score[t][s]; softmax via 8-lane shuffle groups.
// Safe for ctx == q (q fully staged to LDS before any global write).
__global__ __launch_bounds__(256) void attn_kernel(const float* __restrict__ q,
                                                   const float* __restrict__ k,
                                                   const float* __restrict__ v,
                                                   float* __restrict__ ctx) {
    __shared__ float Qs[8 * 260], Ks[8 * 260], Vs[8 * 260];
    int n = blockIdx.x;
    int tid = threadIdx.x;
    size_t base = (size_t)n * 2048;
#pragma unroll
    for (int it = 0; it < 8; ++it) {
        int idx = tid + it * 256;
        int t = idx >> 8, c = idx & 255;
        Qs[t * 260 + c] = q[base + idx];
        Ks[t * 260 + c] = k[base + idx];
        Vs[t * 260 + c] = v[base + idx];
    }
    __syncthreads();
    int wid = tid >> 6, lane = tid & 63;
    int t = lane >> 3, s = lane & 7;
    for (int hh = wid; hh < 8; hh += 4) {
        float acc = 0.f;
        int qb = t * 260 + hh * 32, kb = s * 260 + hh * 32;
#pragma unroll
        for (int jj = 0; jj < 8; ++jj) {
            float4 qv = *(const float4*)&Qs[qb + jj * 4];
            float4 kv = *(const float4*)&Ks[kb + jj * 4];
            acc += qv.x * kv.x + qv.y * kv.y + qv.z * kv.z + qv.w * kv.w;
        }
        acc *= 0.17677669529663687f;            // 1/sqrt(32)
        if (s > t) acc = -1e30f;                // causal mask
        float m = acc;
        m = fmaxf(m, __shfl_xor(m, 1));
        m = fmaxf(m, __shfl_xor(m, 2));
        m = fmaxf(m, __shfl_xor(m, 4));
        float e = __expf(acc - m);
        float sum = e;
        sum += __shfl_xor(sum, 1);
        sum += __shfl_xor(sum, 2);
        sum += __shfl_xor(sum, 4);
        float p = e / sum;
        float a4[4] = {0.f, 0.f, 0.f, 0.f};
        int g = s;
#pragma unroll
        for (int s2 = 0; s2 < 8; ++s2) {
            float ps = __shfl(p, (lane & ~7) | s2);
            int vb = s2 * 260 + hh * 32 + g;
#pragma unroll
            for (int r = 0; r < 4; ++r) a4[r] += ps * Vs[vb + 8 * r];
        }
#pragma unroll
        for (int r = 0; r < 4; ++r)
            ctx[base + t * 256 + hh * 32 + g + 8 * r] = a4[r];
    }
}

// ---------------------------------------------------------------------------
// h = LayerNorm(h + a) * g + b   (in place on h; one wave per 256-wide row)
__global__ __launch_bounds__(64) void ln_kernel(float* __restrict__ h,
                                                const float* __restrict__ a,
                                                const float* __restrict__ g,
                                                const float* __restrict__ b) {
    size_t row = blockIdx.x;
    int lane = threadIdx.x;
    size_t off = row * 256 + lane * 4;
    float4 hv = *(const float4*)&h[off];
    float4 av = *(const float4*)&a[off];
    float4 z = {hv.x + av.x, hv.y + av.y, hv.z + av.z, hv.w + av.w};
    float s = z.x + z.y + z.z + z.w;
    float sq = z.x * z.x + z.y * z.y + z.z * z.z + z.w * z.w;
#pragma unroll
    for (int d = 1; d < 64; d <<= 1) {
        s += __shfl_xor(s, d);
        sq += __shfl_xor(sq, d);
    }
    float mean = s * (1.f / 256.f);
    float var = sq * (1.f / 256.f) - mean * mean;   // biased var
    float inv = 1.0f / sqrtf(var + 1e-5f);
    float4 gv = *(const float4*)&g[lane * 4];
    float4 bv = *(const float4*)&b[lane * 4];
    float4 o;
    o.x = (z.x - mean) * inv * gv.x + bv.x;
    o.y = (z.y - mean) * inv * gv.y + bv.y;
    o.z = (z.z - mean) * inv * gv.z + bv.z;
    o.w = (z.w - mean) * inv * gv.w + bv.w;
    *(float4*)&h[off] = o;
}

// ---------------------------------------------------------------------------
extern "C" void kernel_launch(void* const* d_in, const int* in_sizes, int n_in,
                              void* d_out, int out_size, void* d_ws, size_t ws_size,
                              hipStream_t stream) {
    const float* x   = (const float*)d_in[0];
    const float* Wq  = (const float*)d_in[1];
    const float* bq  = (const float*)d_in[2];
    const float* Wk  = (const float*)d_in[3];
    const float* bk  = (const float*)d_in[4];
    const float* Wv  = (const float*)d_in[5];
    const float* bv  = (const float*)d_in[6];
    const float* Wo  = (const float*)d_in[7];
    const float* bo  = (const float*)d_in[8];
    const float* g1  = (const float*)d_in[9];
    const float* be1 = (const float*)d_in[10];
    const float* W1  = (const float*)d_in[11];
    const float* b1  = (const float*)d_in[12];
    const float* W2  = (const float*)d_in[13];
    const float* b2  = (const float*)d_in[14];
    const float* g2  = (const float*)d_in[15];
    const float* be2 = (const float*)d_in[16];

    // --- workspace-adaptive chunking -------------------------------------
    // Layer is row-local between attention boundaries (attention mixes only
    // within a T=8 sequence), so process M in sequence-aligned chunks.
    // need(nc) = pe(4096) + h(SBUF) + 5 scratch slots of (TOK/nc)*256 floats.
    int nc = 64;
    const int cand[7] = {1, 2, 4, 8, 16, 32, 64};
    for (int ci = 0; ci < 7; ++ci) {
        size_t cS_ = (size_t)(TOK / cand[ci]) * 256;
        size_t need = ((size_t)4096 + (size_t)SBUF + 5 * cS_) * sizeof(float);
        if (need <= ws_size) { nc = cand[ci]; break; }
    }
    const int cM = TOK / nc;            // rows per chunk (multiple of 128)
    const size_t cS = (size_t)cM * 256; // floats per scratch slot

    float* ws = (float*)d_ws;
    float* pe = ws;                     // 2048 used, 4096 reserved
    float* h  = ws + 4096;              // TOK*256
    float* s0 = h + SBUF;               // scratch slot 0 (q / ctx / f1 part)
    float* s1 = s0 + cS;                // k / f1 part
    float* s2 = s1 + cS;                // v / attn_out / f1 part
    float* s3 = s2 + cS;                // f1 part
    float* s4 = s3 + cS;                // f2

    pe_fill<<<8, 256, 0, stream>>>(pe);
    transpose_in<<<dim3(1536, 8, 2), 256, 0, stream>>>(x, pe, h);

    const int gy = cM / 128;            // gemm grid.y per chunk

    for (int l = 0; l < 2; ++l) {
        const float* Wq_l = Wq + (size_t)l * 65536;
        const float* Wk_l = Wk + (size_t)l * 65536;
        const float* Wv_l = Wv + (size_t)l * 65536;
        const float* Wo_l = Wo + (size_t)l * 65536;
        const float* W1_l = W1 + (size_t)l * 262144;
        const float* W2_l = W2 + (size_t)l * 262144;

        for (int ch = 0; ch < nc; ++ch) {
            float* hc = h + (size_t)ch * cS;
            // q,k,v projections
            gemm_kernel<0><<<dim3(2, gy), 256, 0, stream>>>(hc, Wq_l, bq + l * 256, s0, cM, 256, 256);
            gemm_kernel<0><<<dim3(2, gy), 256, 0, stream>>>(hc, Wk_l, bk + l * 256, s1, cM, 256, 256);
            gemm_kernel<0><<<dim3(2, gy), 256, 0, stream>>>(hc, Wv_l, bv + l * 256, s2, cM, 256, 256);
            // attention: ctx overwrites q slot (block-local rows only)
            attn_kernel<<<cM / 8, 256, 0, stream>>>(s0, s1, s2, s0);
            // output projection -> dead v slot
            gemm_kernel<0><<<dim3(2, gy), 256, 0, stream>>>(s0, Wo_l, bo + l * 256, s2, cM, 256, 256);
            ln_kernel<<<cM, 64, 0, stream>>>(hc, s2, g1 + l * 256, be1 + l * 256);
            // FFN: f1 spans slots 0..3, f2 in slot 4
            gemm_kernel<1><<<dim3(8, gy), 256, 0, stream>>>(hc, W1_l, b1 + l * 1024, s0, cM, 1024, 256);
            gemm_kernel<0><<<dim3(2, gy), 256, 0, stream>>>(s0, W2_l, b2 + l * 256, s4, cM, 256, 1024);
            ln_kernel<<<cM, 64, 0, stream>>>(hc, s4, g2 + l * 256, be2 + l * 256);
        }
    }

    transpose_out<<<dim3(192, 8, 2), 256, 0, stream>>>(h, (float*)d_out);
}

// Round 4
// 859.070 us; speedup vs baseline: 4.0126x; 4.0126x over previous
//
#include <hip/hip_runtime.h>
#include <math.h>

// Problem constants: B=4, T=8, C=d=256, H=W=48, L=2, nh=8, dk=32
#define SEQ   9216          // B*H*W
#define TOK   73728         // SEQ*T

typedef short bf16x8 __attribute__((ext_vector_type(8)));
typedef float f32x4  __attribute__((ext_vector_type(4)));

#define GLD_LDS16(gsrc, ldst)                                                      \
    __builtin_amdgcn_global_load_lds(                                              \
        (const __attribute__((address_space(1))) unsigned int*)(gsrc),             \
        (__attribute__((address_space(3))) unsigned int*)(ldst), 16, 0, 0)

__device__ __forceinline__ unsigned short f2bf(float f) {
    unsigned u = __builtin_bit_cast(unsigned, f);
    unsigned r = (u + 0x7fffu + ((u >> 16) & 1u)) >> 16;
    return (unsigned short)r;
}
__device__ __forceinline__ float bf2f(unsigned short h) {
    return __builtin_bit_cast(float, (unsigned)h << 16);
}

// ---------------------------------------------------------------------------
// Positional-encoding table: pe[t*256 + c]
__global__ void pe_fill(float* __restrict__ pe) {
    int idx = blockIdx.x * 256 + threadIdx.x;   // 0..2047
    int t = idx >> 8, c = idx & 255;
    int i2 = c & ~1;
    float div = __expf((float)i2 * (-logf(10000.f) / 256.f));
    float ang = (float)t * div;
    pe[idx] = (c & 1) ? cosf(ang) : sinf(ang);
}

// ---------------------------------------------------------------------------
// fp32 weight -> bf16 (vectorized by 4)
__global__ void convertw(const float* __restrict__ src, unsigned short* __restrict__ dst, int n4) {
    int i = blockIdx.x * 256 + threadIdx.x;
    if (i < n4) {
        float4 v = *(const float4*)(src + (size_t)i * 4);
        unsigned short* o = dst + (size_t)i * 4;
        o[0] = f2bf(v.x); o[1] = f2bf(v.y); o[2] = f2bf(v.z); o[3] = f2bf(v.w);
    }
}

// pack per-layer qkv bias: dst[l*768 + i]
__global__ void pack_bias(const float* __restrict__ bq, const float* __restrict__ bk,
                          const float* __restrict__ bv, float* __restrict__ dst) {
    int l = blockIdx.x, i = threadIdx.x;        // block = 768 threads
    float v = (i < 256) ? bq[l * 256 + i] : (i < 512) ? bk[l * 256 + i - 256]
                                                      : bv[l * 256 + i - 512];
    dst[l * 768 + i] = v;
}

// ---------------------------------------------------------------------------
// x (B,T,C,H,W) -> h (n, t, c) fp32 AND hb bf16, with += pe[t,c].
__global__ __launch_bounds__(256) void transpose_in(const float* __restrict__ x,
                                                    const float* __restrict__ pe,
                                                    float* __restrict__ h,
                                                    unsigned short* __restrict__ hb) {
    int bty = blockIdx.x;
    int y = bty % 48; int bt = bty / 48; int t = bt & 7; int b = bt >> 3;
    int c0 = blockIdx.y * 32, w0 = blockIdx.z * 32;
    __shared__ float tile[32][33];
    int tid = threadIdx.x;
    const float* xp = x + ((size_t)(b * 8 + t) * 256) * 2304 + (size_t)y * 48;
    int wl = tid & 31, cl8 = tid >> 5;
#pragma unroll
    for (int it = 0; it < 4; ++it) {
        int c = c0 + it * 8 + cl8;
        int w = w0 + wl;
        if (w < 48) tile[it * 8 + cl8][wl] = xp[(size_t)c * 2304 + w] + pe[t * 256 + c];
    }
    __syncthreads();
    int cl = tid & 31, wl8 = tid >> 5;
#pragma unroll
    for (int it = 0; it < 4; ++it) {
        int w = w0 + it * 8 + wl8;
        int c = c0 + cl;
        if (w < 48) {
            size_t n = (size_t)(b * 48 + y) * 48 + w;
            float val = tile[cl][it * 8 + wl8];
            size_t off = (n * 8 + t) * 256 + c;
            h[off] = val;
            hb[off] = f2bf(val);
        }
    }
}

// ---------------------------------------------------------------------------
// out (B,C,H,W) = h[n, T-1, c]
__global__ __launch_bounds__(256) void transpose_out(const float* __restrict__ h,
                                                     float* __restrict__ out) {
    int by = blockIdx.x; int y = by % 48, b = by / 48;
    int c0 = blockIdx.y * 32, w0 = blockIdx.z * 32;
    __shared__ float tile[32][33];
    int tid = threadIdx.x;
    int cl = tid & 31, wl8 = tid >> 5;
#pragma unroll
    for (int it = 0; it < 4; ++it) {
        int w = w0 + it * 8 + wl8;
        if (w < 48) {
            size_t n = (size_t)(b * 48 + y) * 48 + w;
            tile[it * 8 + wl8][cl] = h[n * 2048 + 1792 + c0 + cl];
        }
    }
    __syncthreads();
    int wl = tid & 31, cl8 = tid >> 5;
#pragma unroll
    for (int it = 0; it < 4; ++it) {
        int c = c0 + it * 8 + cl8;
        int w = w0 + wl;
        if (w < 48)
            out[((size_t)(b * 256 + c) * 48 + y) * 48 + w] = tile[wl][it * 8 + cl8];
    }
}

// ---------------------------------------------------------------------------
// bf16 MFMA GEMM: C[M,N] = A[M,K](bf16) @ W[N,K]^T(bf16) + bias, opt. GELU.
// 128x128 tile, BK=64, 4 waves x (4x4) 16x16x32 frags. LDS XOR-swizzled
// (16B slot ^= row&7); staged via global_load_lds w=16 with pre-swizzled src.
template <int OUT_BF16, int ACT>
__global__ __launch_bounds__(256) void mgemm(const unsigned short* __restrict__ A,
                                             const unsigned short* __restrict__ W,
                                             const float* __restrict__ bias,
                                             void* __restrict__ Cv,
                                             int M, int N, int K) {
    __shared__ unsigned short As[128 * 64];   // 16 KB
    __shared__ unsigned short Bs[128 * 64];   // 16 KB
    const int tid = threadIdx.x;
    const int m0 = blockIdx.y * 128, n0 = blockIdx.x * 128;
    const int lane = tid & 63, w = tid >> 6;
    const int wr = w >> 1, wc = w & 1;        // wave tile: 64x64
    const int lr = lane & 15, lk = lane >> 4; // frag row/col + k-chunk

    f32x4 acc[4][4] = {};

    // per-thread staging geometry (same for A and B): linear LDS dest,
    // source fetches slot ^ (row&7) so swizzled READS see logical k-chunks.
    int so[4], srow[4], sseg[4];
#pragma unroll
    for (int it = 0; it < 4; ++it) {
        int o = it * 4096 + tid * 16;         // linear byte offset in tile
        so[it] = o;
        srow[it] = o >> 7;                    // 0..127
        int slot = (o >> 4) & 7;
        sseg[it] = slot ^ (srow[it] & 7);     // source k-slot (8 bf16 = 16 B)
    }

    for (int k0 = 0; k0 < K; k0 += 64) {
#pragma unroll
        for (int it = 0; it < 4; ++it) {
            const unsigned short* gB = W + (size_t)(n0 + srow[it]) * K + k0 + sseg[it] * 8;
            GLD_LDS16(gB, (char*)Bs + so[it]);
        }
#pragma unroll
        for (int it = 0; it < 4; ++it) {
            const unsigned short* gA = A + (size_t)(m0 + srow[it]) * K + k0 + sseg[it] * 8;
            GLD_LDS16(gA, (char*)As + so[it]);
        }
        __syncthreads();
#pragma unroll
        for (int kc = 0; kc < 2; ++kc) {
            bf16x8 fA[4], fB[4];
            int slot = kc * 4 + lk;
#pragma unroll
            for (int f = 0; f < 4; ++f) {
                int row = wr * 64 + f * 16 + lr;
                fA[f] = *(const bf16x8*)((const char*)As + row * 128 + ((slot ^ (row & 7)) << 4));
                int col = wc * 64 + f * 16 + lr;
                fB[f] = *(const bf16x8*)((const char*)Bs + col * 128 + ((slot ^ (col & 7)) << 4));
            }
#pragma unroll
            for (int fi = 0; fi < 4; ++fi)
#pragma unroll
                for (int fj = 0; fj < 4; ++fj)
                    acc[fi][fj] = __builtin_amdgcn_mfma_f32_16x16x32_bf16(
                        fA[fi], fB[fj], acc[fi][fj], 0, 0, 0);
        }
        __syncthreads();
    }

    // epilogue: C/D map col=lane&15, row=(lane>>4)*4+reg (m89-verified)
#pragma unroll
    for (int fi = 0; fi < 4; ++fi) {
        int rbase = m0 + wr * 64 + fi * 16 + lk * 4;
#pragma unroll
        for (int fj = 0; fj < 4; ++fj) {
            int col = n0 + wc * 64 + fj * 16 + lr;
            float bv = bias[col];
#pragma unroll
            for (int r = 0; r < 4; ++r) {
                float v = acc[fi][fj][r] + bv;
                if (ACT) v = 0.5f * v * (1.0f + erff(v * 0.70710678118654752f));
                size_t off = (size_t)(rbase + r) * N + col;
                if (OUT_BF16) ((unsigned short*)Cv)[off] = f2bf(v);
                else          ((float*)Cv)[off] = v;
            }
        }
    }
}

// ---------------------------------------------------------------------------
// Causal MHSA: qkv packed bf16 [row][768] (q|k|v), ctx out bf16 [row][256].
// One block per sequence; 4 waves x 2 heads; softmax in 8-lane shuffle groups.
__global__ __launch_bounds__(256) void attn_kernel(const unsigned short* __restrict__ qkv,
                                                   unsigned short* __restrict__ ctx) {
    __shared__ float Qs[8 * 260], Ks[8 * 260], Vs[8 * 260];
    int n = blockIdx.x;
    int tid = threadIdx.x;
    size_t base = (size_t)n * 6144;             // 8*768
#pragma unroll
    for (int it = 0; it < 6; ++it) {
        int i4 = it * 256 + tid;                // 0..1535
        int t = i4 / 192;
        int c4 = (i4 - t * 192) * 4;            // 0..764, mult of 4
        const unsigned short* p = qkv + base + (size_t)t * 768 + c4;
        float4 f = {bf2f(p[0]), bf2f(p[1]), bf2f(p[2]), bf2f(p[3])};
        float* dst = (c4 < 256) ? &Qs[t * 260 + c4]
                   : (c4 < 512) ? &Ks[t * 260 + (c4 - 256)]
                                : &Vs[t * 260 + (c4 - 512)];
        *(float4*)dst = f;
    }
    __syncthreads();
    int wid = tid >> 6, lane = tid & 63;
    int t = lane >> 3, s = lane & 7;
    size_t obase = (size_t)n * 2048;
    for (int hh = wid; hh < 8; hh += 4) {
        float acc = 0.f;
        int qb = t * 260 + hh * 32, kb = s * 260 + hh * 32;
#pragma unroll
        for (int jj = 0; jj < 8; ++jj) {
            float4 qv = *(const float4*)&Qs[qb + jj * 4];
            float4 kv = *(const float4*)&Ks[kb + jj * 4];
            acc += qv.x * kv.x + qv.y * kv.y + qv.z * kv.z + qv.w * kv.w;
        }
        acc *= 0.17677669529663687f;            // 1/sqrt(32)
        if (s > t) acc = -1e30f;
        float m = acc;
        m = fmaxf(m, __shfl_xor(m, 1));
        m = fmaxf(m, __shfl_xor(m, 2));
        m = fmaxf(m, __shfl_xor(m, 4));
        float e = __expf(acc - m);
        float sum = e;
        sum += __shfl_xor(sum, 1);
        sum += __shfl_xor(sum, 2);
        sum += __shfl_xor(sum, 4);
        float p = e / sum;
        float a4[4] = {0.f, 0.f, 0.f, 0.f};
#pragma unroll
        for (int s2 = 0; s2 < 8; ++s2) {
            float ps = __shfl(p, (lane & ~7) | s2);
            int vb = s2 * 260 + hh * 32 + s;
#pragma unroll
            for (int r = 0; r < 4; ++r) a4[r] += ps * Vs[vb + 8 * r];
        }
#pragma unroll
        for (int r = 0; r < 4; ++r)
            ctx[obase + t * 256 + hh * 32 + s + 8 * r] = f2bf(a4[r]);
    }
}

// ---------------------------------------------------------------------------
// h = LayerNorm(h + a) * g + b ; also writes bf16 copy hb. One wave per row.
__global__ __launch_bounds__(64) void ln_kernel(float* __restrict__ h,
                                                unsigned short* __restrict__ hb,
                                                const float* __restrict__ a,
                                                const float* __restrict__ g,
                                                const float* __restrict__ b) {
    size_t row = blockIdx.x;
    int lane = threadIdx.x;
    size_t off = row * 256 + lane * 4;
    float4 hv = *(const float4*)&h[off];
    float4 av = *(const float4*)&a[off];
    float4 z = {hv.x + av.x, hv.y + av.y, hv.z + av.z, hv.w + av.w};
    float s = z.x + z.y + z.z + z.w;
    float sq = z.x * z.x + z.y * z.y + z.z * z.z + z.w * z.w;
#pragma unroll
    for (int d = 1; d < 64; d <<= 1) {
        s += __shfl_xor(s, d);
        sq += __shfl_xor(sq, d);
    }
    float mean = s * (1.f / 256.f);
    float var = sq * (1.f / 256.f) - mean * mean;
    float inv = 1.0f / sqrtf(var + 1e-5f);
    float4 gv = *(const float4*)&g[lane * 4];
    float4 bv = *(const float4*)&b[lane * 4];
    float4 o;
    o.x = (z.x - mean) * inv * gv.x + bv.x;
    o.y = (z.y - mean) * inv * gv.y + bv.y;
    o.z = (z.z - mean) * inv * gv.z + bv.z;
    o.w = (z.w - mean) * inv * gv.w + bv.w;
    *(float4*)&h[off] = o;
    unsigned short* hp = hb + off;
    hp[0] = f2bf(o.x); hp[1] = f2bf(o.y); hp[2] = f2bf(o.z); hp[3] = f2bf(o.w);
}

// ---------------------------------------------------------------------------
extern "C" void kernel_launch(void* const* d_in, const int* in_sizes, int n_in,
                              void* d_out, int out_size, void* d_ws, size_t ws_size,
                              hipStream_t stream) {
    const float* x   = (const float*)d_in[0];
    const float* Wq  = (const float*)d_in[1];
    const float* bq  = (const float*)d_in[2];
    const float* Wk  = (const float*)d_in[3];
    const float* bk  = (const float*)d_in[4];
    const float* Wv  = (const float*)d_in[5];
    const float* bv  = (const float*)d_in[6];
    const float* Wo  = (const float*)d_in[7];
    const float* bo  = (const float*)d_in[8];
    const float* g1  = (const float*)d_in[9];
    const float* be1 = (const float*)d_in[10];
    const float* W1  = (const float*)d_in[11];
    const float* b1  = (const float*)d_in[12];
    const float* W2  = (const float*)d_in[13];
    const float* b2  = (const float*)d_in[14];
    const float* g2  = (const float*)d_in[15];
    const float* be2 = (const float*)d_in[16];

    // ---- workspace layout (bytes) ----
    // nch=1 needs 380,657,664 B; nch=2 needs 248,537,088 B (ws proven >= 264.3 MB).
    char* base = (char*)d_ws;
    const size_t O_PE   = 0;                       // 16 KB reserved
    const size_t O_W    = 16384;                   // bf16 weights, 2 layers
    const size_t WLAYER = 786432ull * 2;           // bytes per layer
    const size_t O_BQ   = O_W + 2 * WLAYER;        // packed qkv bias fp32 (6 KB)
    const size_t O_H    = O_BQ + 8192;             // h fp32: 75,497,472
    const size_t O_HB   = O_H + (size_t)TOK * 256 * 4;   // hb bf16: 37,748,736
    const size_t O_P1   = O_HB + (size_t)TOK * 256 * 2;  // qkv_c / f1o_c pool
    const int nch = (ws_size >= 380657664ull) ? 1 : 2;
    const int Mc = TOK / nch;
    const size_t O_P2 = O_P1 + (size_t)Mc * 2048;  // ctx_c: Mc*512
    const size_t O_P3 = O_P2 + (size_t)Mc * 512;   // ao_c fp32: Mc*1024

    float*          pe   = (float*)(base + O_PE);
    unsigned short* wB   = (unsigned short*)(base + O_W);
    float*          bqkv = (float*)(base + O_BQ);
    float*          h    = (float*)(base + O_H);
    unsigned short* hb   = (unsigned short*)(base + O_HB);
    unsigned short* p1   = (unsigned short*)(base + O_P1); // qkv / f1o
    unsigned short* ctxb = (unsigned short*)(base + O_P2);
    float*          ao   = (float*)(base + O_P3);

    // ---- weight conversion / packing (tiny) ----
    for (int l = 0; l < 2; ++l) {
        unsigned short* wl = wB + (size_t)l * 786432;
        convertw<<<64,  256, 0, stream>>>(Wq + (size_t)l * 65536,  wl,          16384);
        convertw<<<64,  256, 0, stream>>>(Wk + (size_t)l * 65536,  wl + 65536,  16384);
        convertw<<<64,  256, 0, stream>>>(Wv + (size_t)l * 65536,  wl + 131072, 16384);
        convertw<<<64,  256, 0, stream>>>(Wo + (size_t)l * 65536,  wl + 196608, 16384);
        convertw<<<256, 256, 0, stream>>>(W1 + (size_t)l * 262144, wl + 262144, 65536);
        convertw<<<256, 256, 0, stream>>>(W2 + (size_t)l * 262144, wl + 524288, 65536);
    }
    pack_bias<<<2, 768, 0, stream>>>(bq, bk, bv, bqkv);

    pe_fill<<<8, 256, 0, stream>>>(pe);
    transpose_in<<<dim3(1536, 8, 2), 256, 0, stream>>>(x, pe, h, hb);

    const int gy = Mc / 128;
    for (int l = 0; l < 2; ++l) {
        unsigned short* wqkv = wB + (size_t)l * 786432;
        unsigned short* wo   = wqkv + 196608;
        unsigned short* w1   = wqkv + 262144;
        unsigned short* w2   = wqkv + 524288;

        for (int chn = 0; chn < nch; ++chn) {
            size_t moff = (size_t)chn * Mc;
            unsigned short* hbc = hb + moff * 256;
            float*          hc  = h  + moff * 256;
            // qkv projection (one fused GEMM, N=768)
            mgemm<1, 0><<<dim3(6, gy), 256, 0, stream>>>(hbc, wqkv, bqkv + l * 768, p1, Mc, 768, 256);
            // attention
            attn_kernel<<<Mc / 8, 256, 0, stream>>>(p1, ctxb);
            // output projection -> ao (fp32)
            mgemm<0, 0><<<dim3(2, gy), 256, 0, stream>>>(ctxb, wo, bo + l * 256, ao, Mc, 256, 256);
            ln_kernel<<<Mc, 64, 0, stream>>>(hc, hbc, ao, g1 + l * 256, be1 + l * 256);
            // FFN (f1 out bf16 into p1 — qkv dead by now)
            mgemm<1, 1><<<dim3(8, gy), 256, 0, stream>>>(hbc, w1, b1 + l * 1024, p1, Mc, 1024, 256);
            mgemm<0, 0><<<dim3(2, gy), 256, 0, stream>>>(p1, w2, b2 + l * 256, ao, Mc, 256, 1024);
            ln_kernel<<<Mc, 64, 0, stream>>>(hc, hbc, ao, g2 + l * 256, be2 + l * 256);
        }
    }

    transpose_out<<<dim3(192, 8, 2), 256, 0, stream>>>(h, (float*)d_out);
}